// Round 1
// baseline (69.677 us; speedup 1.0000x reference)
//
#include <hip/hip_runtime.h>

#define BATCH      4096
#define NCLS       32
#define NCLASSES   512
#define EMBD       128
#define NEMB       16384   // NCLS * NCLASSES
#define NROWS      (BATCH * NCLS)   // 131072

// ---------------------------------------------------------------------------
// Kernel 1: transpose embeddings (EMBD x NEMB) -> embT (NEMB x EMBD)
// 32x32 LDS tiles, +1 pad to kill bank conflicts. 8.4 MB total -> ~3 us.
// ---------------------------------------------------------------------------
__global__ __launch_bounds__(256) void transpose_emb(
    const float* __restrict__ emb, float* __restrict__ embT) {
    __shared__ float tile[32][33];
    const int e0 = blockIdx.x * 32;   // along NEMB
    const int d0 = blockIdx.y * 32;   // along EMBD
    const int tx = threadIdx.x;       // 0..31  (varies along contiguous dim)
    const int ty = threadIdx.y;       // 0..7

#pragma unroll
    for (int k = 0; k < 32; k += 8) {
        // coalesced read: contiguous in e
        tile[ty + k][tx] = emb[(size_t)(d0 + ty + k) * NEMB + (e0 + tx)];
    }
    __syncthreads();
#pragma unroll
    for (int k = 0; k < 32; k += 8) {
        // coalesced write: contiguous in d
        embT[(size_t)(e0 + ty + k) * EMBD + (d0 + tx)] = tile[tx][ty + k];
    }
}

// ---------------------------------------------------------------------------
// Kernel 2: fused argmax + gather.
// One 64-lane wave per (b,c) row: 512 scores -> argmax (first occurrence)
// -> copy 128-float embedding row to output.
// USE_T: gather from transposed embT (contiguous rows) vs raw emb (columns).
// ---------------------------------------------------------------------------
template <bool USE_T>
__global__ __launch_bounds__(256) void vq_argmax_gather(
    const float* __restrict__ onehot,
    const float* __restrict__ embsrc,   // embT if USE_T, else emb
    float* __restrict__ out) {

    const int wave = threadIdx.x >> 6;                       // 0..3
    const int lane = threadIdx.x & 63;
    const int r    = blockIdx.x * 4 + wave;                  // row id 0..131071
    const float* row = onehot + (size_t)r * NCLASSES;

    // ---- per-lane scan: 8 floats as 2x float4, indices increasing ----
    float v  = -INFINITY;
    int   vi = 0;
#pragma unroll
    for (int half = 0; half < 2; ++half) {
        const int base = half * 256 + lane * 4;
        const float4 x = *reinterpret_cast<const float4*>(row + base);
        const float xs[4] = {x.x, x.y, x.z, x.w};
#pragma unroll
        for (int j = 0; j < 4; ++j) {
            if (xs[j] > v) { v = xs[j]; vi = base + j; }     // strict >: first wins
        }
    }

    // ---- 64-lane butterfly argmax, ties -> smaller index ----
#pragma unroll
    for (int off = 32; off > 0; off >>= 1) {
        const float ov = __shfl_xor(v, off);
        const int   oi = __shfl_xor(vi, off);
        if (ov > v || (ov == v && oi < vi)) { v = ov; vi = oi; }
    }

    const int c    = r & (NCLS - 1);
    const int flat = vi + c * NCLASSES;                      // [0, NEMB)

    // ---- gather 128 floats, lane writes float2 (coalesced 512B/row) ----
    float2* dst = reinterpret_cast<float2*>(out + (size_t)r * EMBD);
    if (USE_T) {
        const float2* src =
            reinterpret_cast<const float2*>(embsrc + (size_t)flat * EMBD);
        dst[lane] = src[lane];
    } else {
        float2 t;
        t.x = embsrc[(size_t)(2 * lane + 0) * NEMB + flat];
        t.y = embsrc[(size_t)(2 * lane + 1) * NEMB + flat];
        dst[lane] = t;
    }
}

extern "C" void kernel_launch(void* const* d_in, const int* in_sizes, int n_in,
                              void* d_out, int out_size, void* d_ws, size_t ws_size,
                              hipStream_t stream) {
    const float* onehot = (const float*)d_in[0];   // (4096, 32, 512) f32
    const float* emb    = (const float*)d_in[1];   // (128, 16384)   f32
    float* out          = (float*)d_out;           // (4096, 4096)   f32

    const size_t embT_bytes = (size_t)NEMB * EMBD * sizeof(float);  // 8.4 MB

    if (ws_size >= embT_bytes) {
        float* embT = (float*)d_ws;
        dim3 tb(32, 8);
        dim3 tg(NEMB / 32, EMBD / 32);
        transpose_emb<<<tg, tb, 0, stream>>>(emb, embT);
        vq_argmax_gather<true><<<NROWS / 4, 256, 0, stream>>>(onehot, embT, out);
    } else {
        vq_argmax_gather<false><<<NROWS / 4, 256, 0, stream>>>(onehot, emb, out);
    }
}

// Round 2
// 69.389 us; speedup vs baseline: 1.0042x; 1.0042x over previous
//
#include <hip/hip_runtime.h>

#define BATCH      4096
#define NCLS       32
#define NCLASSES   512
#define EMBD       128
#define NEMB       16384   // NCLS * NCLASSES
#define NROWS      (BATCH * NCLS)   // 131072

typedef float f4 __attribute__((ext_vector_type(4)));

// ---------------------------------------------------------------------------
// Kernel 1: transpose embeddings (EMBD x NEMB) -> embT (NEMB x EMBD)
// 32x32 LDS tiles, +1 pad. ~17 MB traffic -> ~3 us.
// ---------------------------------------------------------------------------
__global__ __launch_bounds__(256) void transpose_emb(
    const float* __restrict__ emb, float* __restrict__ embT) {
    __shared__ float tile[32][33];
    const int e0 = blockIdx.x * 32;   // along NEMB
    const int d0 = blockIdx.y * 32;   // along EMBD
    const int tx = threadIdx.x;       // 0..31
    const int ty = threadIdx.y;       // 0..7

#pragma unroll
    for (int k = 0; k < 32; k += 8) {
        tile[ty + k][tx] = emb[(size_t)(d0 + ty + k) * NEMB + (e0 + tx)];
    }
    __syncthreads();
#pragma unroll
    for (int k = 0; k < 32; k += 8) {
        embT[(size_t)(e0 + ty + k) * EMBD + (d0 + tx)] = tile[tx][ty + k];
    }
}

// ---------------------------------------------------------------------------
// Kernel 2: fused argmax + gather. TWO rows per 64-lane wave:
// lanes 0-31 own row 2*rp, lanes 32-63 own row 2*rp+1. Each half-wave scans
// 512 scores (16/lane as 4x float4), butterfly-argmaxes within its 32 lanes
// (xor offsets <32 never cross the half boundary), then the full wave writes
// both 512B output rows as one contiguous 1KB float4 store.
// Streaming traffic (onehot in, out) is nontemporal so embT stays cached.
// ---------------------------------------------------------------------------
template <bool USE_T>
__global__ __launch_bounds__(256) void vq_argmax_gather(
    const float* __restrict__ onehot,
    const float* __restrict__ embsrc,   // embT if USE_T, else emb
    float* __restrict__ out) {

    const int wave = threadIdx.x >> 6;                 // 0..3
    const int lane = threadIdx.x & 63;
    const int half = lane >> 5;                        // 0 or 1
    const int hl   = lane & 31;                        // lane within half
    const int rp   = blockIdx.x * 4 + wave;            // row-pair id
    const int r    = rp * 2 + half;                    // this half's row
    const float* row = onehot + (size_t)r * NCLASSES;

    // ---- per-lane scan: 16 floats as 4x float4, indices increasing ----
    float v  = -INFINITY;
    int   vi = 0;
#pragma unroll
    for (int k = 0; k < 4; ++k) {
        const int base = hl * 4 + k * 128;
        const f4 x = __builtin_nontemporal_load(
            reinterpret_cast<const f4*>(row + base));
#pragma unroll
        for (int j = 0; j < 4; ++j) {
            if (x[j] > v) { v = x[j]; vi = base + j; }  // strict >: first wins
        }
    }

    // ---- 32-lane butterfly argmax within each half, ties -> smaller idx ----
#pragma unroll
    for (int off = 16; off > 0; off >>= 1) {
        const float ov = __shfl_xor(v, off);
        const int   oi = __shfl_xor(vi, off);
        if (ov > v || (ov == v && oi < vi)) { v = ov; vi = oi; }
    }

    const int c    = r & (NCLS - 1);
    const int flat = vi + c * NCLASSES;                 // [0, NEMB)

    // ---- gather 128 floats/row; lane does one float4 (16B) ----
    f4* dst = reinterpret_cast<f4*>(out + (size_t)r * EMBD);
    if (USE_T) {
        const f4* src = reinterpret_cast<const f4*>(embsrc + (size_t)flat * EMBD);
        const f4 val = src[hl];                         // cached (L2/L3 resident)
        __builtin_nontemporal_store(val, &dst[hl]);     // wave: 1KB contiguous
    } else {
        f4 t;
#pragma unroll
        for (int j = 0; j < 4; ++j)
            t[j] = embsrc[(size_t)(4 * hl + j) * NEMB + flat];
        __builtin_nontemporal_store(t, &dst[hl]);
    }
}

extern "C" void kernel_launch(void* const* d_in, const int* in_sizes, int n_in,
                              void* d_out, int out_size, void* d_ws, size_t ws_size,
                              hipStream_t stream) {
    const float* onehot = (const float*)d_in[0];   // (4096, 32, 512) f32
    const float* emb    = (const float*)d_in[1];   // (128, 16384)   f32
    float* out          = (float*)d_out;           // (4096, 4096)   f32

    const size_t embT_bytes = (size_t)NEMB * EMBD * sizeof(float);  // 8.4 MB

    if (ws_size >= embT_bytes) {
        float* embT = (float*)d_ws;
        dim3 tb(32, 8);
        dim3 tg(NEMB / 32, EMBD / 32);
        transpose_emb<<<tg, tb, 0, stream>>>(emb, embT);
        // 8 rows per 256-thread block (2 rows per wave)
        vq_argmax_gather<true><<<NROWS / 8, 256, 0, stream>>>(onehot, embT, out);
    } else {
        vq_argmax_gather<false><<<NROWS / 8, 256, 0, stream>>>(onehot, emb, out);
    }
}